// Round 4
// baseline (298.873 us; speedup 1.0000x reference)
//
#include <hip/hip_runtime.h>
#include <hip/hip_bf16.h>
#include <stdint.h>

// Problem constants
#define BB 4
#define LL 4096
#define DD 1024
#define HH 16
#define WW 128
#define DH 64
#define NWIN 32            // LL / WW
#define MTOT (BB*LL)       // 16384
#define NQKV (3*DD)        // 3072

typedef short bf16x8 __attribute__((ext_vector_type(8)));
typedef float f32x4 __attribute__((ext_vector_type(4)));
typedef unsigned short u16;

__device__ __forceinline__ u16 f2bf(float f) {
    union { float f; uint32_t u; } v; v.f = f;
    uint32_t u = v.u;
    uint32_t r = (u + 0x7fffu + ((u >> 16) & 1u)) >> 16;
    return (u16)r;
}

// async global->LDS, 16 bytes per lane, HW dest = wave-uniform base + lane*16
#define GLOAD_LDS16(gptr, ldsptr)                                                        \
    __builtin_amdgcn_global_load_lds((const __attribute__((address_space(1))) void*)(gptr), \
                                     (__attribute__((address_space(3))) void*)(ldsptr),      \
                                     16, 0, 0)

// ---------------- fp32 -> bf16 conversion (vectorized) ----------------
__global__ __launch_bounds__(256) void cvt_f32_bf16(const float* __restrict__ in,
                                                    u16* __restrict__ out, int n8) {
    int i = blockIdx.x * blockDim.x + threadIdx.x;
    int stride = gridDim.x * blockDim.x;
    for (; i < n8; i += stride) {
        const float4* p = (const float4*)(in + (size_t)i * 8);
        float4 a = p[0], b = p[1];
        bf16x8 o;
        o[0] = (short)f2bf(a.x); o[1] = (short)f2bf(a.y);
        o[2] = (short)f2bf(a.z); o[3] = (short)f2bf(a.w);
        o[4] = (short)f2bf(b.x); o[5] = (short)f2bf(b.y);
        o[6] = (short)f2bf(b.z); o[7] = (short)f2bf(b.w);
        *(bf16x8*)(out + (size_t)i * 8) = o;
    }
}

// =====================================================================
// 256x256-tile GEMM core, BK=32, K=1024, 512 threads = 8 waves (2M x 4N).
// 4-slot LDS rotation (4 x 32KB), counted vmcnt(8) pipeline, raw barriers.
// LDS half layout: [128 rows][32 cols] packed 2 rows / 128B physical row:
//   logical (r, kbyte) -> prow = r>>1, off = (r&1)*64 + kbyte
// (spreads frag reads uniformly over banks; gload_lds writes linear with
//  per-lane pre-permuted global source.)
// =====================================================================

#define VM8 asm volatile("s_waitcnt vmcnt(8)" ::: "memory")
#define VM4 asm volatile("s_waitcnt vmcnt(4)" ::: "memory")
#define VM0 asm volatile("s_waitcnt vmcnt(0)" ::: "memory")

#define MFMA4x4(MB)                                                                             \
    acc[(MB)+0][0] = __builtin_amdgcn_mfma_f32_16x16x32_bf16(af0, bf0, acc[(MB)+0][0], 0,0,0);  \
    acc[(MB)+1][0] = __builtin_amdgcn_mfma_f32_16x16x32_bf16(af1, bf0, acc[(MB)+1][0], 0,0,0);  \
    acc[(MB)+2][0] = __builtin_amdgcn_mfma_f32_16x16x32_bf16(af2, bf0, acc[(MB)+2][0], 0,0,0);  \
    acc[(MB)+3][0] = __builtin_amdgcn_mfma_f32_16x16x32_bf16(af3, bf0, acc[(MB)+3][0], 0,0,0);  \
    acc[(MB)+0][1] = __builtin_amdgcn_mfma_f32_16x16x32_bf16(af0, bf1, acc[(MB)+0][1], 0,0,0);  \
    acc[(MB)+1][1] = __builtin_amdgcn_mfma_f32_16x16x32_bf16(af1, bf1, acc[(MB)+1][1], 0,0,0);  \
    acc[(MB)+2][1] = __builtin_amdgcn_mfma_f32_16x16x32_bf16(af2, bf1, acc[(MB)+2][1], 0,0,0);  \
    acc[(MB)+3][1] = __builtin_amdgcn_mfma_f32_16x16x32_bf16(af3, bf1, acc[(MB)+3][1], 0,0,0);  \
    acc[(MB)+0][2] = __builtin_amdgcn_mfma_f32_16x16x32_bf16(af0, bf2, acc[(MB)+0][2], 0,0,0);  \
    acc[(MB)+1][2] = __builtin_amdgcn_mfma_f32_16x16x32_bf16(af1, bf2, acc[(MB)+1][2], 0,0,0);  \
    acc[(MB)+2][2] = __builtin_amdgcn_mfma_f32_16x16x32_bf16(af2, bf2, acc[(MB)+2][2], 0,0,0);  \
    acc[(MB)+3][2] = __builtin_amdgcn_mfma_f32_16x16x32_bf16(af3, bf2, acc[(MB)+3][2], 0,0,0);  \
    acc[(MB)+0][3] = __builtin_amdgcn_mfma_f32_16x16x32_bf16(af0, bf3, acc[(MB)+0][3], 0,0,0);  \
    acc[(MB)+1][3] = __builtin_amdgcn_mfma_f32_16x16x32_bf16(af1, bf3, acc[(MB)+1][3], 0,0,0);  \
    acc[(MB)+2][3] = __builtin_amdgcn_mfma_f32_16x16x32_bf16(af2, bf3, acc[(MB)+2][3], 0,0,0);  \
    acc[(MB)+3][3] = __builtin_amdgcn_mfma_f32_16x16x32_bf16(af3, bf3, acc[(MB)+3][3], 0,0,0);

// One K-tile = 2 phases. S = slot (compile-time), sj = K-tile index being
// staged (runtime, uniform), STG = whether to stage, VM = vmcnt statement.
#define KTILE(S, sj, STG, VM) do {                                                              \
    char* sb = lds + (S)*32768;                                                                 \
    /* ---- phase A: frags m0-3 + all B; stage h0 halves of K-tile sj ---- */                   \
    af0 = *(const bf16x8*)(sb + aoff);                                                          \
    af1 = *(const bf16x8*)(sb + aoff + 1024);                                                   \
    af2 = *(const bf16x8*)(sb + aoff + 2048);                                                   \
    af3 = *(const bf16x8*)(sb + aoff + 3072);                                                   \
    bf0 = *(const bf16x8*)(sb + boff);                                                          \
    bf1 = *(const bf16x8*)(sb + boff + 1024);                                                   \
    bf2 = *(const bf16x8*)(sb + boff + 2048);                                                   \
    bf3 = *(const bf16x8*)(sb + boff + 3072);                                                   \
    if (STG) {                                                                                  \
        GLOAD_LDS16(asrc0 + (size_t)(sj)*32, lds + (((S)+3)&3)*32768 + wave*1024);              \
        GLOAD_LDS16(bsrc0 + (size_t)(sj)*32, lds + (((S)+3)&3)*32768 + 16384 + wave*1024);      \
    }                                                                                           \
    __builtin_amdgcn_s_barrier();                                                               \
    asm volatile("s_waitcnt lgkmcnt(0)" ::: "memory");                                          \
    __builtin_amdgcn_sched_barrier(0);                                                          \
    __builtin_amdgcn_s_setprio(1);                                                              \
    MFMA4x4(0)                                                                                  \
    __builtin_amdgcn_s_setprio(0);                                                              \
    __builtin_amdgcn_s_barrier();                                                               \
    /* ---- phase B: frags m4-7 (B reused); stage h1 halves ---- */                             \
    af0 = *(const bf16x8*)(sb + aoff + 4096);                                                   \
    af1 = *(const bf16x8*)(sb + aoff + 5120);                                                   \
    af2 = *(const bf16x8*)(sb + aoff + 6144);                                                   \
    af3 = *(const bf16x8*)(sb + aoff + 7168);                                                   \
    if (STG) {                                                                                  \
        GLOAD_LDS16(asrc1 + (size_t)(sj)*32, lds + (((S)+3)&3)*32768 + 8192 + wave*1024);       \
        GLOAD_LDS16(bsrc1 + (size_t)(sj)*32, lds + (((S)+3)&3)*32768 + 24576 + wave*1024);      \
    }                                                                                           \
    __builtin_amdgcn_s_barrier();                                                               \
    asm volatile("s_waitcnt lgkmcnt(0)" ::: "memory");                                          \
    __builtin_amdgcn_sched_barrier(0);                                                          \
    __builtin_amdgcn_s_setprio(1);                                                              \
    MFMA4x4(4)                                                                                  \
    __builtin_amdgcn_s_setprio(0);                                                              \
    VM;                                                                                         \
    __builtin_amdgcn_sched_barrier(0);                                                          \
    __builtin_amdgcn_s_barrier();                                                               \
} while (0)

// Bijective XCD-chunked block swizzle; col-major (bx = sw/64, by = sw%64).
__device__ __forceinline__ void map_block(int& bx, int& by) {
    int nwg = gridDim.x;             // multiple of 8
    int wg  = blockIdx.x;
    int chunk = nwg >> 3;
    int sw = (wg & 7) * chunk + (wg >> 3);
    by = sw & 63;                    // 64 M-tiles
    bx = sw >> 6;
}

// Core: computes acc[8][4] for this block/wave. A:[16384][1024], Bw:[N][1024] bf16.
__device__ __forceinline__ void gemm256_core(const u16* __restrict__ A,
                                             const u16* __restrict__ Bw,
                                             int row0, int col0,
                                             char* lds, f32x4 acc[8][4]) {
    const int tid  = threadIdx.x;
    const int lane = tid & 63;
    const int wave = tid >> 6;
    const int wm   = wave >> 2;          // 0..1
    const int wn   = wave & 3;           // 0..3
    const int colb = lane & 15;
    const int kgrp = lane >> 4;          // 0..3

    // fragment-read byte offsets within a slot (packed layout)
    const int soff = ((colb & 1) * 4 + kgrp) * 16;
    const int aoff = wm * 8192 + (colb >> 1) * 128 + soff;
    const int boff = 16384 + (wn >> 1) * 8192 + ((wn & 1) * 32 + (colb >> 1)) * 128 + soff;

    // stage source mapping (inverse of packed layout), per thread
    const int lrow  = ((tid >> 3) << 1) | ((tid & 7) >> 2);   // 0..127 within half
    const int lkoff = (tid & 3) * 8;                          // 0/8/16/24 elems
    const u16* asrc0 = A  + (size_t)(row0 + lrow) * 1024 + lkoff;
    const u16* asrc1 = A  + (size_t)(row0 + 128 + lrow) * 1024 + lkoff;
    const u16* bsrc0 = Bw + (size_t)(col0 + lrow) * 1024 + lkoff;
    const u16* bsrc1 = Bw + (size_t)(col0 + 128 + lrow) * 1024 + lkoff;

    #pragma unroll
    for (int m = 0; m < 8; ++m)
        #pragma unroll
        for (int n = 0; n < 4; ++n)
            acc[m][n] = (f32x4){0.f, 0.f, 0.f, 0.f};

    bf16x8 af0, af1, af2, af3, bf0, bf1, bf2, bf3;

    // ---- prologue: stage K-tiles 0,1,2 into slots 0,1,2 (12 loads/thread) ----
    #pragma unroll
    for (int jj = 0; jj < 3; ++jj) {
        GLOAD_LDS16(asrc0 + jj * 32, lds + jj * 32768 + wave * 1024);
        GLOAD_LDS16(bsrc0 + jj * 32, lds + jj * 32768 + 16384 + wave * 1024);
        GLOAD_LDS16(asrc1 + jj * 32, lds + jj * 32768 + 8192 + wave * 1024);
        GLOAD_LDS16(bsrc1 + jj * 32, lds + jj * 32768 + 24576 + wave * 1024);
    }
    VM8;                                   // K-tile 0 landed (K1,K2 may be in flight)
    __builtin_amdgcn_sched_barrier(0);
    __builtin_amdgcn_s_barrier();

    // ---- main loop: j = 0..27, staging j+3 ----
    for (int jb = 0; jb < 28; jb += 4) {
        KTILE(0, jb + 3, 1, VM8);
        KTILE(1, jb + 4, 1, VM8);
        KTILE(2, jb + 5, 1, VM8);
        KTILE(3, jb + 6, 1, VM8);
    }
    // ---- tail: j = 28..31 ----
    KTILE(0, 31, 1, VM8);                  // j=28 stages K31
    KTILE(1, 0, 0, VM4);                   // j=29
    KTILE(2, 0, 0, VM0);                   // j=30
    KTILE(3, 0, 0, VM0);                   // j=31
}

// ---------------- Kernel 1: QKV GEMM + bias + scatter to windowed q/k/vT ----------------
__global__ __launch_bounds__(512, 2) void qkv_gemm_kernel(const u16* __restrict__ xb,
                                                          const u16* __restrict__ wb,
                                                          const float* __restrict__ bias,
                                                          u16* __restrict__ qd,
                                                          u16* __restrict__ kd,
                                                          u16* __restrict__ vtd) {
    __shared__ char g_lds[131072];
    f32x4 acc[8][4];
    int bx, by;
    map_block(bx, by);
    const int row0 = by * 256;
    const int col0 = bx * 256;
    gemm256_core(xb, wb, row0, col0, g_lds, acc);

    const int lane = threadIdx.x & 63;
    const int wave = threadIdx.x >> 6;
    const int wm = wave >> 2, wn = wave & 3;
    const int colb = lane & 15;
    const int rgrp = lane >> 4;

    #pragma unroll
    for (int m = 0; m < 8; ++m) {
        #pragma unroll
        for (int n = 0; n < 4; ++n) {
            #pragma unroll
            for (int j = 0; j < 4; ++j) {
                int gm = row0 + wm * 128 + m * 16 + rgrp * 4 + j;
                int gn = col0 + wn * 64 + n * 16 + colb;
                float v = acc[m][n][j] + bias[gn];
                int which = gn >> 10, c = gn & 1023, h = c >> 6, d = c & 63;
                int b = gm >> 12, l = gm & 4095, n0 = l >> 7, wq = l & 127;
                size_t wbase = (size_t)((b * HH + h) * NWIN + n0) * (WW * DH);
                if (which == 0)      qd [wbase + wq * 64 + d] = f2bf(v * 0.125f);
                else if (which == 1) kd [wbase + wq * 64 + d] = f2bf(v);
                else                 vtd[wbase + d * 128 + wq] = f2bf(v);
            }
        }
    }
}

// ---------------- Kernel 3: output projection GEMM + bias -> fp32 out ----------------
__global__ __launch_bounds__(512, 2) void out_gemm_kernel(const u16* __restrict__ ab,
                                                          const u16* __restrict__ wb,
                                                          const float* __restrict__ bias,
                                                          float* __restrict__ out) {
    __shared__ char g_lds[131072];
    f32x4 acc[8][4];
    int bx, by;
    map_block(bx, by);
    const int row0 = by * 256;
    const int col0 = bx * 256;
    gemm256_core(ab, wb, row0, col0, g_lds, acc);

    const int lane = threadIdx.x & 63;
    const int wave = threadIdx.x >> 6;
    const int wm = wave >> 2, wn = wave & 3;
    const int colb = lane & 15;
    const int rgrp = lane >> 4;

    #pragma unroll
    for (int m = 0; m < 8; ++m) {
        #pragma unroll
        for (int n = 0; n < 4; ++n) {
            #pragma unroll
            for (int j = 0; j < 4; ++j) {
                int gm = row0 + wm * 128 + m * 16 + rgrp * 4 + j;
                int gn = col0 + wn * 64 + n * 16 + colb;
                out[(size_t)gm * DD + gn] = acc[m][n][j] + bias[gn];
            }
        }
    }
}

// ---------------- Kernel 2: windowed causal attention (unchanged) ----------------
__global__ __launch_bounds__(256) void attn_kernel(const u16* __restrict__ q,
                                                   const u16* __restrict__ k,
                                                   const u16* __restrict__ vt,
                                                   u16* __restrict__ aout) {
    __shared__ u16 Ps[4][32 * 136];   // per-wave P tile, padded rows

    const int win = blockIdx.x;          // 0..2047
    const int b  = win >> 9;
    const int h  = (win >> 5) & 15;
    const int n0 = win & 31;
    const u16* qp = q  + (size_t)win * (WW * DH);
    const u16* kp = k  + (size_t)win * (WW * DH);
    const u16* vp = vt + (size_t)win * (WW * DH);

    const int lane = threadIdx.x & 63;
    const int wave = threadIdx.x >> 6;
    const int wrow = wave * 32;
    const int colb = lane & 15;
    const int kgrp = lane >> 4;
    const int rgrp = kgrp;

    f32x4 s[2][8];
    #pragma unroll
    for (int m = 0; m < 2; ++m)
        #pragma unroll
        for (int n = 0; n < 8; ++n)
            s[m][n] = (f32x4){0.f, 0.f, 0.f, 0.f};

    #pragma unroll
    for (int kk = 0; kk < 2; ++kk) {
        bf16x8 aq[2];
        #pragma unroll
        for (int m = 0; m < 2; ++m)
            aq[m] = *(const bf16x8*)&qp[(wrow + m * 16 + colb) * 64 + kk * 32 + kgrp * 8];
        #pragma unroll
        for (int n = 0; n < 8; ++n) {
            bf16x8 bk = *(const bf16x8*)&kp[(n * 16 + colb) * 64 + kk * 32 + kgrp * 8];
            s[0][n] = __builtin_amdgcn_mfma_f32_16x16x32_bf16(aq[0], bk, s[0][n], 0, 0, 0);
            s[1][n] = __builtin_amdgcn_mfma_f32_16x16x32_bf16(aq[1], bk, s[1][n], 0, 0, 0);
        }
    }

    #pragma unroll
    for (int m = 0; m < 2; ++m) {
        #pragma unroll
        for (int j = 0; j < 4; ++j) {
            int row = wrow + m * 16 + rgrp * 4 + j;
            float vals[8];
            float mx = -1e30f;
            #pragma unroll
            for (int n = 0; n < 8; ++n) {
                int col = n * 16 + colb;
                float v = s[m][n][j];
                if (col > row) v = -1e30f;
                vals[n] = v;
                mx = fmaxf(mx, v);
            }
            #pragma unroll
            for (int off = 1; off < 16; off <<= 1)
                mx = fmaxf(mx, __shfl_xor(mx, off, 64));
            float sum = 0.f;
            #pragma unroll
            for (int n = 0; n < 8; ++n) {
                float p = __expf(vals[n] - mx);
                vals[n] = p;
                sum += p;
            }
            #pragma unroll
            for (int off = 1; off < 16; off <<= 1)
                sum += __shfl_xor(sum, off, 64);
            float r = 1.0f / sum;
            #pragma unroll
            for (int n = 0; n < 8; ++n)
                Ps[wave][(m * 16 + rgrp * 4 + j) * 136 + n * 16 + colb] = f2bf(vals[n] * r);
        }
    }
    __syncthreads();

    f32x4 o[2][4];
    #pragma unroll
    for (int m = 0; m < 2; ++m)
        #pragma unroll
        for (int n = 0; n < 4; ++n)
            o[m][n] = (f32x4){0.f, 0.f, 0.f, 0.f};

    #pragma unroll
    for (int kk = 0; kk < 4; ++kk) {
        bf16x8 ap[2];
        #pragma unroll
        for (int m = 0; m < 2; ++m)
            ap[m] = *(const bf16x8*)&Ps[wave][(m * 16 + colb) * 136 + kk * 32 + kgrp * 8];
        #pragma unroll
        for (int n = 0; n < 4; ++n) {
            bf16x8 bv = *(const bf16x8*)&vp[(n * 16 + colb) * 128 + kk * 32 + kgrp * 8];
            o[0][n] = __builtin_amdgcn_mfma_f32_16x16x32_bf16(ap[0], bv, o[0][n], 0, 0, 0);
            o[1][n] = __builtin_amdgcn_mfma_f32_16x16x32_bf16(ap[1], bv, o[1][n], 0, 0, 0);
        }
    }

    #pragma unroll
    for (int m = 0; m < 2; ++m) {
        #pragma unroll
        for (int n = 0; n < 4; ++n) {
            #pragma unroll
            for (int j = 0; j < 4; ++j) {
                int row = wrow + m * 16 + rgrp * 4 + j;
                int l = n0 * 128 + row;
                int d = h * 64 + n * 16 + colb;
                aout[((size_t)(b * LL + l)) * DD + d] = f2bf(o[m][n][j]);
            }
        }
    }
}

// ---------------- launch ----------------
extern "C" void kernel_launch(void* const* d_in, const int* in_sizes, int n_in,
                              void* d_out, int out_size, void* d_ws, size_t ws_size,
                              hipStream_t stream) {
    const float* x     = (const float*)d_in[0];
    const float* qkv_w = (const float*)d_in[1];
    const float* qkv_b = (const float*)d_in[2];
    const float* out_w = (const float*)d_in[3];
    const float* out_b = (const float*)d_in[4];
    float* out = (float*)d_out;

    char* ws = (char*)d_ws;
    u16* xb   = (u16*)(ws);                           // 16,777,216 elems (reused as attn_out)
    u16* qwb  = (u16*)(ws + 33554432);                // 3,145,728 elems
    u16* owb  = (u16*)(ws + 39845888);                // 1,048,576 elems
    u16* qws  = (u16*)(ws + 41943040);
    u16* kws  = (u16*)(ws + 75497472);
    u16* vtws = (u16*)(ws + 109051904);

    cvt_f32_bf16<<<2048, 256, 0, stream>>>(x, xb, 16777216 / 8);
    cvt_f32_bf16<<<1536, 256, 0, stream>>>(qkv_w, qwb, 3145728 / 8);
    cvt_f32_bf16<<<512, 256, 0, stream>>>(out_w, owb, 1048576 / 8);

    qkv_gemm_kernel<<<(MTOT / 256) * (NQKV / 256), 512, 0, stream>>>(xb, qwb, qkv_b, qws, kws, vtws);

    attn_kernel<<<BB * HH * NWIN, 256, 0, stream>>>(qws, kws, vtws, xb /* attn_out */);

    out_gemm_kernel<<<(MTOT / 256) * (DD / 256), 512, 0, stream>>>(xb, owb, out_b, out);
}

// Round 5
// 292.309 us; speedup vs baseline: 1.0225x; 1.0225x over previous
//
#include <hip/hip_runtime.h>
#include <hip/hip_bf16.h>
#include <stdint.h>

// Problem constants
#define BB 4
#define LL 4096
#define DD 1024
#define HH 16
#define WW 128
#define DH 64
#define NWIN 32            // LL / WW
#define MTOT (BB*LL)       // 16384
#define NQKV (3*DD)        // 3072

typedef short bf16x8 __attribute__((ext_vector_type(8)));
typedef float f32x4 __attribute__((ext_vector_type(4)));
typedef unsigned short u16;

__device__ __forceinline__ u16 f2bf(float f) {
    union { float f; uint32_t u; } v; v.f = f;
    uint32_t u = v.u;
    uint32_t r = (u + 0x7fffu + ((u >> 16) & 1u)) >> 16;
    return (u16)r;
}

// async global->LDS, 16 bytes per lane, HW dest = wave-uniform base + lane*16
#define GLOAD_LDS16(gptr, ldsptr)                                                        \
    __builtin_amdgcn_global_load_lds((const __attribute__((address_space(1))) void*)(gptr), \
                                     (__attribute__((address_space(3))) void*)(ldsptr),      \
                                     16, 0, 0)

// ---------------- fp32 -> bf16 conversion (vectorized) ----------------
__global__ __launch_bounds__(256) void cvt_f32_bf16(const float* __restrict__ in,
                                                    u16* __restrict__ out, int n8) {
    int i = blockIdx.x * blockDim.x + threadIdx.x;
    int stride = gridDim.x * blockDim.x;
    for (; i < n8; i += stride) {
        const float4* p = (const float4*)(in + (size_t)i * 8);
        float4 a = p[0], b = p[1];
        bf16x8 o;
        o[0] = (short)f2bf(a.x); o[1] = (short)f2bf(a.y);
        o[2] = (short)f2bf(a.z); o[3] = (short)f2bf(a.w);
        o[4] = (short)f2bf(b.x); o[5] = (short)f2bf(b.y);
        o[6] = (short)f2bf(b.z); o[7] = (short)f2bf(b.w);
        *(bf16x8*)(out + (size_t)i * 8) = o;
    }
}

// =====================================================================
// 256x256-tile GEMM core, BK=32, K=1024, 512 threads = 8 waves (2M x 4N).
// 4-slot LDS rotation (4 x 32KB), counted vmcnt(8) pipeline, raw barriers.
//
// LDS half-tile layout (XOR-swizzled, T2): logical (row R in 0..127,
// 16B-slot g in 0..3, byte b) lives at physical
//     p = R*64 + ((g ^ ((R>>1)&3)) << 4) + b.
// Fragment rows are m*16+colb -> swizzle idx = kgrp ^ ((colb>>1)&3)
// (m-independent), so frag strides stay +1024.
// gload_lds writes linearly (thread t -> physical t*16 within a half), so
// the SOURCE global address carries the inverse permutation:
//     row = t>>2, k-elems = ((t&3) ^ ((t>>3)&3))*8.
// Per 16-lane frag-read group: all 8 16B slots x 2 lanes = free 2-way.
// =====================================================================

#define VM8 asm volatile("s_waitcnt vmcnt(8)" ::: "memory")
#define VM4 asm volatile("s_waitcnt vmcnt(4)" ::: "memory")
#define VM0 asm volatile("s_waitcnt vmcnt(0)" ::: "memory")

#define MFMA4x4(MB)                                                                             \
    acc[(MB)+0][0] = __builtin_amdgcn_mfma_f32_16x16x32_bf16(af0, bf0, acc[(MB)+0][0], 0,0,0);  \
    acc[(MB)+1][0] = __builtin_amdgcn_mfma_f32_16x16x32_bf16(af1, bf0, acc[(MB)+1][0], 0,0,0);  \
    acc[(MB)+2][0] = __builtin_amdgcn_mfma_f32_16x16x32_bf16(af2, bf0, acc[(MB)+2][0], 0,0,0);  \
    acc[(MB)+3][0] = __builtin_amdgcn_mfma_f32_16x16x32_bf16(af3, bf0, acc[(MB)+3][0], 0,0,0);  \
    acc[(MB)+0][1] = __builtin_amdgcn_mfma_f32_16x16x32_bf16(af0, bf1, acc[(MB)+0][1], 0,0,0);  \
    acc[(MB)+1][1] = __builtin_amdgcn_mfma_f32_16x16x32_bf16(af1, bf1, acc[(MB)+1][1], 0,0,0);  \
    acc[(MB)+2][1] = __builtin_amdgcn_mfma_f32_16x16x32_bf16(af2, bf1, acc[(MB)+2][1], 0,0,0);  \
    acc[(MB)+3][1] = __builtin_amdgcn_mfma_f32_16x16x32_bf16(af3, bf1, acc[(MB)+3][1], 0,0,0);  \
    acc[(MB)+0][2] = __builtin_amdgcn_mfma_f32_16x16x32_bf16(af0, bf2, acc[(MB)+0][2], 0,0,0);  \
    acc[(MB)+1][2] = __builtin_amdgcn_mfma_f32_16x16x32_bf16(af1, bf2, acc[(MB)+1][2], 0,0,0);  \
    acc[(MB)+2][2] = __builtin_amdgcn_mfma_f32_16x16x32_bf16(af2, bf2, acc[(MB)+2][2], 0,0,0);  \
    acc[(MB)+3][2] = __builtin_amdgcn_mfma_f32_16x16x32_bf16(af3, bf2, acc[(MB)+3][2], 0,0,0);  \
    acc[(MB)+0][3] = __builtin_amdgcn_mfma_f32_16x16x32_bf16(af0, bf3, acc[(MB)+0][3], 0,0,0);  \
    acc[(MB)+1][3] = __builtin_amdgcn_mfma_f32_16x16x32_bf16(af1, bf3, acc[(MB)+1][3], 0,0,0);  \
    acc[(MB)+2][3] = __builtin_amdgcn_mfma_f32_16x16x32_bf16(af2, bf3, acc[(MB)+2][3], 0,0,0);  \
    acc[(MB)+3][3] = __builtin_amdgcn_mfma_f32_16x16x32_bf16(af3, bf3, acc[(MB)+3][3], 0,0,0);

// One K-tile = 2 phases. S = slot (compile-time), sj = K-tile index being
// staged (runtime, uniform), STG = whether to stage, VM = vmcnt statement.
#define KTILE(S, sj, STG, VM) do {                                                              \
    char* sb = lds + (S)*32768;                                                                 \
    /* ---- phase A: frags m0-3 + all B; stage h0 halves of K-tile sj ---- */                   \
    af0 = *(const bf16x8*)(sb + aoff);                                                          \
    af1 = *(const bf16x8*)(sb + aoff + 1024);                                                   \
    af2 = *(const bf16x8*)(sb + aoff + 2048);                                                   \
    af3 = *(const bf16x8*)(sb + aoff + 3072);                                                   \
    bf0 = *(const bf16x8*)(sb + boff);                                                          \
    bf1 = *(const bf16x8*)(sb + boff + 1024);                                                   \
    bf2 = *(const bf16x8*)(sb + boff + 2048);                                                   \
    bf3 = *(const bf16x8*)(sb + boff + 3072);                                                   \
    if (STG) {                                                                                  \
        GLOAD_LDS16(asrc0 + (size_t)(sj)*32, lds + (((S)+3)&3)*32768 + wave*1024);              \
        GLOAD_LDS16(bsrc0 + (size_t)(sj)*32, lds + (((S)+3)&3)*32768 + 16384 + wave*1024);      \
    }                                                                                           \
    __builtin_amdgcn_s_barrier();                                                               \
    asm volatile("s_waitcnt lgkmcnt(0)" ::: "memory");                                          \
    __builtin_amdgcn_sched_barrier(0);                                                          \
    __builtin_amdgcn_s_setprio(1);                                                              \
    MFMA4x4(0)                                                                                  \
    __builtin_amdgcn_s_setprio(0);                                                              \
    __builtin_amdgcn_s_barrier();                                                               \
    /* ---- phase B: frags m4-7 (B reused); stage h1 halves ---- */                             \
    af0 = *(const bf16x8*)(sb + aoff + 4096);                                                   \
    af1 = *(const bf16x8*)(sb + aoff + 5120);                                                   \
    af2 = *(const bf16x8*)(sb + aoff + 6144);                                                   \
    af3 = *(const bf16x8*)(sb + aoff + 7168);                                                   \
    if (STG) {                                                                                  \
        GLOAD_LDS16(asrc1 + (size_t)(sj)*32, lds + (((S)+3)&3)*32768 + 8192 + wave*1024);       \
        GLOAD_LDS16(bsrc1 + (size_t)(sj)*32, lds + (((S)+3)&3)*32768 + 24576 + wave*1024);      \
    }                                                                                           \
    __builtin_amdgcn_s_barrier();                                                               \
    asm volatile("s_waitcnt lgkmcnt(0)" ::: "memory");                                          \
    __builtin_amdgcn_sched_barrier(0);                                                          \
    __builtin_amdgcn_s_setprio(1);                                                              \
    MFMA4x4(4)                                                                                  \
    __builtin_amdgcn_s_setprio(0);                                                              \
    VM;                                                                                         \
    __builtin_amdgcn_sched_barrier(0);                                                          \
    __builtin_amdgcn_s_barrier();                                                               \
} while (0)

// Bijective XCD-chunked block swizzle; col-major (bx = sw/64, by = sw%64).
__device__ __forceinline__ void map_block(int& bx, int& by) {
    int nwg = gridDim.x;             // multiple of 8
    int wg  = blockIdx.x;
    int chunk = nwg >> 3;
    int sw = (wg & 7) * chunk + (wg >> 3);
    by = sw & 63;                    // 64 M-tiles
    bx = sw >> 6;
}

// Core: computes acc[8][4] for this block/wave. A:[16384][1024], Bw:[N][1024] bf16.
__device__ __forceinline__ void gemm256_core(const u16* __restrict__ A,
                                             const u16* __restrict__ Bw,
                                             int row0, int col0,
                                             char* lds, f32x4 acc[8][4]) {
    const int tid  = threadIdx.x;
    const int lane = tid & 63;
    const int wave = tid >> 6;
    const int wm   = wave >> 2;          // 0..1
    const int wn   = wave & 3;           // 0..3
    const int colb = lane & 15;
    const int kgrp = lane >> 4;          // 0..3

    // fragment-read byte offsets within a slot (XOR-swizzled layout)
    const int swz  = (kgrp ^ ((colb >> 1) & 3)) << 4;
    const int aoff = wm * 8192 + colb * 64 + swz;
    const int boff = 16384 + (wn >> 1) * 8192 + (wn & 1) * 4096 + colb * 64 + swz;

    // stage source mapping (inverse swizzle), per thread
    const int lrow  = tid >> 2;                               // 0..127 within half
    const int lkoff = ((tid & 3) ^ ((tid >> 3) & 3)) * 8;     // swizzled k-elems
    const u16* asrc0 = A  + (size_t)(row0 + lrow) * 1024 + lkoff;
    const u16* asrc1 = A  + (size_t)(row0 + 128 + lrow) * 1024 + lkoff;
    const u16* bsrc0 = Bw + (size_t)(col0 + lrow) * 1024 + lkoff;
    const u16* bsrc1 = Bw + (size_t)(col0 + 128 + lrow) * 1024 + lkoff;

    #pragma unroll
    for (int m = 0; m < 8; ++m)
        #pragma unroll
        for (int n = 0; n < 4; ++n)
            acc[m][n] = (f32x4){0.f, 0.f, 0.f, 0.f};

    bf16x8 af0, af1, af2, af3, bf0, bf1, bf2, bf3;

    // ---- prologue: stage K-tiles 0,1,2 into slots 0,1,2 (12 loads/thread) ----
    #pragma unroll
    for (int jj = 0; jj < 3; ++jj) {
        GLOAD_LDS16(asrc0 + jj * 32, lds + jj * 32768 + wave * 1024);
        GLOAD_LDS16(bsrc0 + jj * 32, lds + jj * 32768 + 16384 + wave * 1024);
        GLOAD_LDS16(asrc1 + jj * 32, lds + jj * 32768 + 8192 + wave * 1024);
        GLOAD_LDS16(bsrc1 + jj * 32, lds + jj * 32768 + 24576 + wave * 1024);
    }
    VM8;                                   // K-tile 0 landed (K1,K2 may be in flight)
    __builtin_amdgcn_sched_barrier(0);
    __builtin_amdgcn_s_barrier();

    // ---- main loop: j = 0..27, staging j+3 ----
    for (int jb = 0; jb < 28; jb += 4) {
        KTILE(0, jb + 3, 1, VM8);
        KTILE(1, jb + 4, 1, VM8);
        KTILE(2, jb + 5, 1, VM8);
        KTILE(3, jb + 6, 1, VM8);
    }
    // ---- tail: j = 28..31 ----
    KTILE(0, 31, 1, VM8);                  // j=28 stages K31
    KTILE(1, 0, 0, VM4);                   // j=29
    KTILE(2, 0, 0, VM0);                   // j=30
    KTILE(3, 0, 0, VM0);                   // j=31
}

// ---------------- Kernel 1: QKV GEMM + bias + scatter to windowed q/k/vT ----------------
__global__ __launch_bounds__(512, 2) void qkv_gemm_kernel(const u16* __restrict__ xb,
                                                          const u16* __restrict__ wb,
                                                          const float* __restrict__ bias,
                                                          u16* __restrict__ qd,
                                                          u16* __restrict__ kd,
                                                          u16* __restrict__ vtd) {
    __shared__ char g_lds[131072];
    f32x4 acc[8][4];
    int bx, by;
    map_block(bx, by);
    const int row0 = by * 256;
    const int col0 = bx * 256;
    gemm256_core(xb, wb, row0, col0, g_lds, acc);

    const int lane = threadIdx.x & 63;
    const int wave = threadIdx.x >> 6;
    const int wm = wave >> 2, wn = wave & 3;
    const int colb = lane & 15;
    const int rgrp = lane >> 4;

    #pragma unroll
    for (int m = 0; m < 8; ++m) {
        #pragma unroll
        for (int n = 0; n < 4; ++n) {
            #pragma unroll
            for (int j = 0; j < 4; ++j) {
                int gm = row0 + wm * 128 + m * 16 + rgrp * 4 + j;
                int gn = col0 + wn * 64 + n * 16 + colb;
                float v = acc[m][n][j] + bias[gn];
                int which = gn >> 10, c = gn & 1023, h = c >> 6, d = c & 63;
                int b = gm >> 12, l = gm & 4095, n0 = l >> 7, wq = l & 127;
                size_t wbase = (size_t)((b * HH + h) * NWIN + n0) * (WW * DH);
                if (which == 0)      qd [wbase + wq * 64 + d] = f2bf(v * 0.125f);
                else if (which == 1) kd [wbase + wq * 64 + d] = f2bf(v);
                else                 vtd[wbase + d * 128 + wq] = f2bf(v);
            }
        }
    }
}

// ---------------- Kernel 3: output projection GEMM + bias -> fp32 out ----------------
__global__ __launch_bounds__(512, 2) void out_gemm_kernel(const u16* __restrict__ ab,
                                                          const u16* __restrict__ wb,
                                                          const float* __restrict__ bias,
                                                          float* __restrict__ out) {
    __shared__ char g_lds[131072];
    f32x4 acc[8][4];
    int bx, by;
    map_block(bx, by);
    const int row0 = by * 256;
    const int col0 = bx * 256;
    gemm256_core(ab, wb, row0, col0, g_lds, acc);

    const int lane = threadIdx.x & 63;
    const int wave = threadIdx.x >> 6;
    const int wm = wave >> 2, wn = wave & 3;
    const int colb = lane & 15;
    const int rgrp = lane >> 4;

    #pragma unroll
    for (int m = 0; m < 8; ++m) {
        #pragma unroll
        for (int n = 0; n < 4; ++n) {
            #pragma unroll
            for (int j = 0; j < 4; ++j) {
                int gm = row0 + wm * 128 + m * 16 + rgrp * 4 + j;
                int gn = col0 + wn * 64 + n * 16 + colb;
                out[(size_t)gm * DD + gn] = acc[m][n][j] + bias[gn];
            }
        }
    }
}

// ---------------- Kernel 2: windowed causal attention (unchanged) ----------------
__global__ __launch_bounds__(256) void attn_kernel(const u16* __restrict__ q,
                                                   const u16* __restrict__ k,
                                                   const u16* __restrict__ vt,
                                                   u16* __restrict__ aout) {
    __shared__ u16 Ps[4][32 * 136];   // per-wave P tile, padded rows

    const int win = blockIdx.x;          // 0..2047
    const int b  = win >> 9;
    const int h  = (win >> 5) & 15;
    const int n0 = win & 31;
    const u16* qp = q  + (size_t)win * (WW * DH);
    const u16* kp = k  + (size_t)win * (WW * DH);
    const u16* vp = vt + (size_t)win * (WW * DH);

    const int lane = threadIdx.x & 63;
    const int wave = threadIdx.x >> 6;
    const int wrow = wave * 32;
    const int colb = lane & 15;
    const int kgrp = lane >> 4;
    const int rgrp = kgrp;

    f32x4 s[2][8];
    #pragma unroll
    for (int m = 0; m < 2; ++m)
        #pragma unroll
        for (int n = 0; n < 8; ++n)
            s[m][n] = (f32x4){0.f, 0.f, 0.f, 0.f};

    #pragma unroll
    for (int kk = 0; kk < 2; ++kk) {
        bf16x8 aq[2];
        #pragma unroll
        for (int m = 0; m < 2; ++m)
            aq[m] = *(const bf16x8*)&qp[(wrow + m * 16 + colb) * 64 + kk * 32 + kgrp * 8];
        #pragma unroll
        for (int n = 0; n < 8; ++n) {
            bf16x8 bk = *(const bf16x8*)&kp[(n * 16 + colb) * 64 + kk * 32 + kgrp * 8];
            s[0][n] = __builtin_amdgcn_mfma_f32_16x16x32_bf16(aq[0], bk, s[0][n], 0, 0, 0);
            s[1][n] = __builtin_amdgcn_mfma_f32_16x16x32_bf16(aq[1], bk, s[1][n], 0, 0, 0);
        }
    }

    #pragma unroll
    for (int m = 0; m < 2; ++m) {
        #pragma unroll
        for (int j = 0; j < 4; ++j) {
            int row = wrow + m * 16 + rgrp * 4 + j;
            float vals[8];
            float mx = -1e30f;
            #pragma unroll
            for (int n = 0; n < 8; ++n) {
                int col = n * 16 + colb;
                float v = s[m][n][j];
                if (col > row) v = -1e30f;
                vals[n] = v;
                mx = fmaxf(mx, v);
            }
            #pragma unroll
            for (int off = 1; off < 16; off <<= 1)
                mx = fmaxf(mx, __shfl_xor(mx, off, 64));
            float sum = 0.f;
            #pragma unroll
            for (int n = 0; n < 8; ++n) {
                float p = __expf(vals[n] - mx);
                vals[n] = p;
                sum += p;
            }
            #pragma unroll
            for (int off = 1; off < 16; off <<= 1)
                sum += __shfl_xor(sum, off, 64);
            float r = 1.0f / sum;
            #pragma unroll
            for (int n = 0; n < 8; ++n)
                Ps[wave][(m * 16 + rgrp * 4 + j) * 136 + n * 16 + colb] = f2bf(vals[n] * r);
        }
    }
    __syncthreads();

    f32x4 o[2][4];
    #pragma unroll
    for (int m = 0; m < 2; ++m)
        #pragma unroll
        for (int n = 0; n < 4; ++n)
            o[m][n] = (f32x4){0.f, 0.f, 0.f, 0.f};

    #pragma unroll
    for (int kk = 0; kk < 4; ++kk) {
        bf16x8 ap[2];
        #pragma unroll
        for (int m = 0; m < 2; ++m)
            ap[m] = *(const bf16x8*)&Ps[wave][(m * 16 + colb) * 136 + kk * 32 + kgrp * 8];
        #pragma unroll
        for (int n = 0; n < 4; ++n) {
            bf16x8 bv = *(const bf16x8*)&vp[(n * 16 + colb) * 128 + kk * 32 + kgrp * 8];
            o[0][n] = __builtin_amdgcn_mfma_f32_16x16x32_bf16(ap[0], bv, o[0][n], 0, 0, 0);
            o[1][n] = __builtin_amdgcn_mfma_f32_16x16x32_bf16(ap[1], bv, o[1][n], 0, 0, 0);
        }
    }

    #pragma unroll
    for (int m = 0; m < 2; ++m) {
        #pragma unroll
        for (int n = 0; n < 4; ++n) {
            #pragma unroll
            for (int j = 0; j < 4; ++j) {
                int row = wrow + m * 16 + rgrp * 4 + j;
                int l = n0 * 128 + row;
                int d = h * 64 + n * 16 + colb;
                aout[((size_t)(b * LL + l)) * DD + d] = f2bf(o[m][n][j]);
            }
        }
    }
}

// ---------------- launch ----------------
extern "C" void kernel_launch(void* const* d_in, const int* in_sizes, int n_in,
                              void* d_out, int out_size, void* d_ws, size_t ws_size,
                              hipStream_t stream) {
    const float* x     = (const float*)d_in[0];
    const float* qkv_w = (const float*)d_in[1];
    const float* qkv_b = (const float*)d_in[2];
    const float* out_w = (const float*)d_in[3];
    const float* out_b = (const float*)d_in[4];
    float* out = (float*)d_out;

    char* ws = (char*)d_ws;
    u16* xb   = (u16*)(ws);                           // 16,777,216 elems (reused as attn_out)
    u16* qwb  = (u16*)(ws + 33554432);                // 3,145,728 elems
    u16* owb  = (u16*)(ws + 39845888);                // 1,048,576 elems
    u16* qws  = (u16*)(ws + 41943040);
    u16* kws  = (u16*)(ws + 75497472);
    u16* vtws = (u16*)(ws + 109051904);

    cvt_f32_bf16<<<2048, 256, 0, stream>>>(x, xb, 16777216 / 8);
    cvt_f32_bf16<<<1536, 256, 0, stream>>>(qkv_w, qwb, 3145728 / 8);
    cvt_f32_bf16<<<512, 256, 0, stream>>>(out_w, owb, 1048576 / 8);

    qkv_gemm_kernel<<<(MTOT / 256) * (NQKV / 256), 512, 0, stream>>>(xb, qwb, qkv_b, qws, kws, vtws);

    attn_kernel<<<BB * HH * NWIN, 256, 0, stream>>>(qws, kws, vtws, xb /* attn_out */);

    out_gemm_kernel<<<(MTOT / 256) * (DD / 256), 512, 0, stream>>>(xb, owb, out_b, out);
}